// Round 4
// baseline (440.717 us; speedup 1.0000x reference)
//
#include <hip/hip_runtime.h>
#include <stdint.h>

#define N_TOK 262144
#define DIM 64
#define K_CODES 1024
#define OUT_LOSS_OFF (N_TOK * DIM)      // 16777216
#define OUT_IDX_OFF (N_TOK * DIM + 1)   // 16777217

// Certified |d_approx - d_exact| <= ~1.1e-4 worst case (fp16 w-term
// 2^-11*||2z||*||w|| <= 8.9e-5 at ||z||<=11.5, + outer rounding 1.5e-5,
// + split residuals ~1e-7). MARGIN = 4e-4 gives 1.8x headroom.
#define MARGIN 4e-4f

typedef _Float16 half8 __attribute__((ext_vector_type(8)));
typedef float f32x4 __attribute__((ext_vector_type(4)));
typedef unsigned int uint32x4 __attribute__((ext_vector_type(4)));

// ---- LDS layout (byte offsets into one block) ----
#define SM_WF 0          // fp16 w*1024, 1024 rows x 128B, chunk-XOR swizzled
#define SM_SW2 131072    // float[1024]  ||w_c||^2 (np-pairwise exact)
#define SM_SZ2 135168    // float[256]   ||z_t||^2 (np-pairwise exact)
#define SM_M1 136192     // float[256] screening top-4 values + 3 indices
#define SM_M2 137216
#define SM_M3 138240
#define SM_M4 139264
#define SM_I1 140288
#define SM_I2 141312
#define SM_I3 142336
#define SM_IDX 143360    // int[256] final index per token
#define SM_FBC 144384    // int fallback counter
#define SM_FBL 144388    // int[256] fallback token list
#define SM_RED 145416    // double[16] loss partials
#define SM_FBK 145544    // u64 fallback argmin key
#define SM_BYTES 145552

// numpy pairwise sum of squares over 64 contiguous fp32, STREAMING form:
// identical operation order to the reference pairwise sum (8 accumulators,
// unroll-8, paired combine) but never holds more than 16 values live.
__device__ __forceinline__ float np_sumsq64_stream(const float4* p) {
#pragma clang fp contract(off)
  float r[8];
  {
    float4 a = p[0], b = p[1];
    r[0] = a.x * a.x;
    r[1] = a.y * a.y;
    r[2] = a.z * a.z;
    r[3] = a.w * a.w;
    r[4] = b.x * b.x;
    r[5] = b.y * b.y;
    r[6] = b.z * b.z;
    r[7] = b.w * b.w;
  }
#pragma unroll
  for (int i = 1; i < 8; ++i) {
    float4 a = p[2 * i], b = p[2 * i + 1];
    r[0] += a.x * a.x;
    r[1] += a.y * a.y;
    r[2] += a.z * a.z;
    r[3] += a.w * a.w;
    r[4] += b.x * b.x;
    r[5] += b.y * b.y;
    r[6] += b.z * b.z;
    r[7] += b.w * b.w;
  }
  return ((r[0] + r[1]) + (r[2] + r[3])) + ((r[4] + r[5]) + (r[6] + r[7]));
}

// The ORIGINAL bit-exact distance: d = fl(fl(s_z2+s_w2) - chain64((2z)*w)),
// sequential ascending k. Must match numpy/BLAS exactly -> argmin-identical.
__device__ __forceinline__ float exact_dist(const float* __restrict__ z,
                                            long long t, int c,
                                            const float* __restrict__ w,
                                            float s_z2v, float w2) {
  const float4* zp = (const float4*)(z + (size_t)t * DIM);
  const float4* wp = (const float4*)(w + (size_t)c * DIM);
  float a = 0.f;
#pragma unroll
  for (int i = 0; i < 16; ++i) {
    float4 zv = zp[i];
    float4 pv = wp[i];
    a = __builtin_fmaf(zv.x + zv.x, pv.x, a);
    a = __builtin_fmaf(zv.y + zv.y, pv.y, a);
    a = __builtin_fmaf(zv.z + zv.z, pv.z, a);
    a = __builtin_fmaf(zv.w + zv.w, pv.w, a);
  }
  return (s_z2v + w2) - a;
}

// Branchless sorted insert into 4-deep (values) / 3-deep (indices) list.
__device__ __forceinline__ void ins4(float d, int c, float& m1, float& m2,
                                     float& m3, float& m4, int& i1, int& i2,
                                     int& i3) {
  bool b1 = d < m1, b2 = d < m2, b3 = d < m3, b4 = d < m4;
  m4 = b3 ? m3 : (b4 ? d : m4);
  m3 = b2 ? m2 : (b3 ? d : m3);
  i3 = b2 ? i2 : (b3 ? c : i3);
  m2 = b1 ? m1 : (b2 ? d : m2);
  i2 = b1 ? i1 : (b2 ? c : i2);
  m1 = b1 ? d : m1;
  i1 = b1 ? c : i1;
}

// Build one k-half MFMA A-frag pair from 8 z floats: hi = fp16(2z),
// lo = fp16((2z - hi) * 4096). Recombined with exact power-of-2 scales
// (w is scaled by 1024 -> C1=2^-10, C2=2^-22).
__device__ __forceinline__ void make_afrag(float4 a, float4 b, half8& hi,
                                           half8& lo) {
  float v[8] = {a.x, a.y, a.z, a.w, b.x, b.y, b.z, b.w};
  uint32x4 uh, ul;
#pragma unroll
  for (int j = 0; j < 4; ++j) {
    float x0 = v[2 * j] + v[2 * j];
    float x1 = v[2 * j + 1] + v[2 * j + 1];
    _Float16 h0 = (_Float16)x0, h1 = (_Float16)x1;
    float r0 = (x0 - (float)h0) * 4096.f;
    float r1 = (x1 - (float)h1) * 4096.f;
    _Float16 l0 = (_Float16)r0, l1 = (_Float16)r1;
    uh[j] = (unsigned)__builtin_bit_cast(unsigned short, h0) |
            ((unsigned)__builtin_bit_cast(unsigned short, h1) << 16);
    ul[j] = (unsigned)__builtin_bit_cast(unsigned short, l0) |
            ((unsigned)__builtin_bit_cast(unsigned short, l1) << 16);
  }
  hi = __builtin_bit_cast(half8, uh);
  lo = __builtin_bit_cast(half8, ul);
}

// One block = 256 tokens, 1024 threads (16 waves). Screen all 1024 codes via
// mfma_f32_16x16x32_f16 (wave: 16 tokens x 16-code tiles), track top-4, then
// exact-eval only margin candidates with the original bit-exact chain.
// R6: LDS (146KB) pins 1 block/CU = exactly 4 waves/SIMD, so occupancy
// above that is impossible -- state the matching VGPR budget explicitly:
// waves_per_eu(4,4) -> 128 VGPRs. R5 ran at VGPR_Count=64 and spilled
// (~57MB scratch round-trip, VALU 3x inflated). Prologues restructured to
// stream (8 regs live) instead of materializing 64-float arrays.
__global__ __attribute__((amdgpu_flat_work_group_size(1024, 1024),
                          amdgpu_waves_per_eu(4, 4))) void vq_main_k(
    const float* __restrict__ z, const float* __restrict__ w,
    float* __restrict__ out, double* __restrict__ loss_acc) {
#pragma clang fp contract(off)
  __shared__ __align__(16) char smem[SM_BYTES];
  char* wf = smem + SM_WF;
  float* sw2 = (float*)(smem + SM_SW2);
  float* sz2 = (float*)(smem + SM_SZ2);
  float* sm1 = (float*)(smem + SM_M1);
  float* sm2 = (float*)(smem + SM_M2);
  float* sm3 = (float*)(smem + SM_M3);
  float* sm4 = (float*)(smem + SM_M4);
  int* si1 = (int*)(smem + SM_I1);
  int* si2 = (int*)(smem + SM_I2);
  int* si3 = (int*)(smem + SM_I3);
  int* sidx = (int*)(smem + SM_IDX);
  int* fbc = (int*)(smem + SM_FBC);
  int* fbl = (int*)(smem + SM_FBL);
  double* red = (double*)(smem + SM_RED);
  unsigned long long* fbk = (unsigned long long*)(smem + SM_FBK);

  const int tid = (int)threadIdx.x;
  const int lane = tid & 63;
  const int wid = tid >> 6;  // 16 waves

  if (tid == 0) *fbc = 0;

  // ---- prologue A: per-code ||w||^2 + fp16(w*1024) staged to LDS ----
  // Streaming: per 8-float chunk, update the 8 pairwise accumulators (exact
  // numpy order) AND pack/store the fp16 chunk. Max ~20 regs live.
  {
    const int c = tid;  // 1024 threads = 1024 codes
    const float4* wp = (const float4*)(w + (size_t)c * DIM);
    float r[8];
#pragma unroll
    for (int ch = 0; ch < 8; ++ch) {
      float4 a = wp[2 * ch], b = wp[2 * ch + 1];
      float x[8] = {a.x, a.y, a.z, a.w, b.x, b.y, b.z, b.w};
      if (ch == 0) {
#pragma unroll
        for (int j = 0; j < 8; ++j) r[j] = x[j] * x[j];
      } else {
#pragma unroll
        for (int j = 0; j < 8; ++j) r[j] += x[j] * x[j];
      }
      uint32x4 pk;
#pragma unroll
      for (int j = 0; j < 4; ++j) {
        _Float16 h0 = (_Float16)(x[2 * j] * 1024.f);
        _Float16 h1 = (_Float16)(x[2 * j + 1] * 1024.f);
        pk[j] = (unsigned)__builtin_bit_cast(unsigned short, h0) |
                ((unsigned)__builtin_bit_cast(unsigned short, h1) << 16);
      }
      // chunk ch holds k = ch*8..+7; stored at slot ch^(c&7) (bank-balanced)
      *(uint32x4*)(wf + c * 128 + ((ch ^ (c & 7)) << 4)) = pk;
    }
    sw2[c] = ((r[0] + r[1]) + (r[2] + r[3])) + ((r[4] + r[5]) + (r[6] + r[7]));
  }
  // ---- prologue B: per-token ||z||^2 (np-pairwise exact, streaming) ----
  if (tid < 256) {
    long long gt = (long long)blockIdx.x * 256 + tid;
    sz2[tid] = np_sumsq64_stream((const float4*)(z + (size_t)gt * DIM));
  }
  __syncthreads();

  // ---- screening: wave handles 16 tokens x all 1024 codes ----
  {
    const int wtok = wid * 16;
    const int g = lane >> 4;  // k-group
    // A-frags: token = wtok + (lane&15), k = g*8..+7 (khalf0), 32+g*8 (khalf1)
    half8 ah0, al0, ah1, al1;
    {
      long long gA = ((long long)blockIdx.x * 256 + wtok + (lane & 15)) * DIM;
      const float* zr = z + gA + g * 8;
      make_afrag(*(const float4*)(zr), *(const float4*)(zr + 4), ah0, al0);
      make_afrag(*(const float4*)(zr + 32), *(const float4*)(zr + 36), ah1,
                 al1);
    }
    // acc rows: token = wtok + g*4 + r
    float sz[4];
#pragma unroll
    for (int r = 0; r < 4; ++r) sz[r] = sz2[wtok + g * 4 + r];

    float m1[4], m2[4], m3[4], m4[4];
    int i1[4], i2[4], i3[4];
#pragma unroll
    for (int r = 0; r < 4; ++r) {
      m1[r] = m2[r] = m3[r] = m4[r] = 3.4e38f;
      i1[r] = i2[r] = i3[r] = 0;
    }

    const float C1 = 1.f / 1024.f;            // undo w*1024
    const float C2 = 1.f / (1024.f * 4096.f); // undo w*1024 and zlo*4096

#pragma unroll 2
    for (int ct = 0; ct < 64; ++ct) {
      const int cc = (ct << 4) | (lane & 15);
      float w2c = sw2[cc];
      const char* wrow = wf + cc * 128;
      half8 b0 = __builtin_bit_cast(
          half8, *(const uint32x4*)(wrow + ((g ^ (cc & 7)) << 4)));
      half8 b1 = __builtin_bit_cast(
          half8, *(const uint32x4*)(wrow + (((4 + g) ^ (cc & 7)) << 4)));
      f32x4 acch = {0.f, 0.f, 0.f, 0.f};
      f32x4 accl = {0.f, 0.f, 0.f, 0.f};
      acch = __builtin_amdgcn_mfma_f32_16x16x32_f16(ah0, b0, acch, 0, 0, 0);
      accl = __builtin_amdgcn_mfma_f32_16x16x32_f16(al0, b0, accl, 0, 0, 0);
      acch = __builtin_amdgcn_mfma_f32_16x16x32_f16(ah1, b1, acch, 0, 0, 0);
      accl = __builtin_amdgcn_mfma_f32_16x16x32_f16(al1, b1, accl, 0, 0, 0);
#pragma unroll
      for (int r = 0; r < 4; ++r) {
        float dot = __builtin_fmaf(accl[r], C2, acch[r] * C1);
        float d = (sz[r] + w2c) - dot;
        ins4(d, cc, m1[r], m2[r], m3[r], m4[r], i1[r], i2[r], i3[r]);
      }
    }

    // butterfly merge across the 16 lanes sharing this token set
#pragma unroll
    for (int s = 1; s <= 8; s <<= 1) {
#pragma unroll
      for (int r = 0; r < 4; ++r) {
        float bm1 = __shfl_xor(m1[r], s, 64);
        float bm2 = __shfl_xor(m2[r], s, 64);
        float bm3 = __shfl_xor(m3[r], s, 64);
        float bm4 = __shfl_xor(m4[r], s, 64);
        int bi1 = __shfl_xor(i1[r], s, 64);
        int bi2 = __shfl_xor(i2[r], s, 64);
        int bi3 = __shfl_xor(i3[r], s, 64);
        ins4(bm1, bi1, m1[r], m2[r], m3[r], m4[r], i1[r], i2[r], i3[r]);
        ins4(bm2, bi2, m1[r], m2[r], m3[r], m4[r], i1[r], i2[r], i3[r]);
        ins4(bm3, bi3, m1[r], m2[r], m3[r], m4[r], i1[r], i2[r], i3[r]);
        m4[r] = fminf(m4[r], bm4);
      }
    }
    if ((lane & 15) == 0) {
#pragma unroll
      for (int r = 0; r < 4; ++r) {
        int tk = wtok + g * 4 + r;
        sm1[tk] = m1[r];
        sm2[tk] = m2[r];
        sm3[tk] = m3[r];
        sm4[tk] = m4[r];
        si1[tk] = i1[r];
        si2[tk] = i2[r];
        si3[tk] = i3[r];
      }
    }
  }
  __syncthreads();

  // ---- phase 1: resolve index per token (threads 0..255) ----
  if (tid < 256) {
    const int tok = tid;
    float v1 = sm1[tok], v2 = sm2[tok], v3 = sm3[tok], v4 = sm4[tok];
    float thr = v1 + MARGIN;
    int idx = si1[tok];
    if (v2 <= thr) {
      if (v4 <= thr) {
        // >=4 candidates in margin: rare, full exact scan cooperatively later
        int p = atomicAdd(fbc, 1);
        fbl[p] = tok;
        idx = -1;
      } else {
        long long gt = (long long)blockIdx.x * 256 + tok;
        float sz2v = sz2[tok];
        int ca = si1[tok], cb = si2[tok], cc2 = si3[tok];
        int n = (v3 <= thr) ? 3 : 2;
        int t;
        if (cb < ca) { t = ca; ca = cb; cb = t; }
        if (n == 3) {
          if (cc2 < cb) { t = cb; cb = cc2; cc2 = t; }
          if (cb < ca) { t = ca; ca = cb; cb = t; }
        }
        // exact eval ascending index, strict '<' => numpy first-min-wins
        float bd = exact_dist(z, gt, ca, w, sz2v, sw2[ca]);
        idx = ca;
        float d2 = exact_dist(z, gt, cb, w, sz2v, sw2[cb]);
        if (d2 < bd) { bd = d2; idx = cb; }
        if (n == 3) {
          float d3 = exact_dist(z, gt, cc2, w, sz2v, sw2[cc2]);
          if (d3 < bd) { bd = d3; idx = cc2; }
        }
      }
    }
    if (idx >= 0) sidx[tok] = idx;
  }
  __syncthreads();

  // ---- phase 2: cooperative exact fallback (expected ~0 per block) ----
  {
    int nfb = *fbc;
    for (int f = 0; f < nfb; ++f) {
      int tok = fbl[f];
      if (tid == 0) *fbk = ~0ull;
      __syncthreads();
      long long gt = (long long)blockIdx.x * 256 + tok;
      float d = exact_dist(z, gt, tid, w, sz2[tok], sw2[tid]);
      // positive d: float bit pattern is order-preserving; idx in low bits
      unsigned long long key =
          ((unsigned long long)__builtin_bit_cast(unsigned int, d) << 32) |
          (unsigned)tid;
#pragma unroll
      for (int off = 32; off > 0; off >>= 1) {
        unsigned long long o = __shfl_down(key, off, 64);
        key = (o < key) ? o : key;
      }
      if (lane == 0) atomicMin(fbk, key);
      __syncthreads();
      if (tid == 0) sidx[tok] = (int)((*fbk) & 0xffffffffu);
    }
  }
  __syncthreads();

  // ---- phase 3: outputs. thread -> (token, quarter of 16 floats) ----
  {
    const int tok = tid >> 2, q = tid & 3;
    const long long gt = (long long)blockIdx.x * 256 + tok;
    const int idx = sidx[tok];
    const float4* zp = (const float4*)(z + (size_t)gt * DIM) + q * 4;
    const float4* wp = (const float4*)(w + (size_t)idx * DIM) + q * 4;
    float4* op = (float4*)(out + (size_t)gt * DIM) + q * 4;
    double ls = 0.0;
#pragma unroll
    for (int i = 0; i < 4; ++i) {
      float4 wv = wp[i];
      float4 zv = zp[i];
      op[i] = wv;
      double d0 = (double)wv.x - (double)zv.x;
      double d1 = (double)wv.y - (double)zv.y;
      double d2 = (double)wv.z - (double)zv.z;
      double d3 = (double)wv.w - (double)zv.w;
      ls = __builtin_fma(d0, d0, ls);
      ls = __builtin_fma(d1, d1, ls);
      ls = __builtin_fma(d2, d2, ls);
      ls = __builtin_fma(d3, d3, ls);
    }
    if (q == 0) out[OUT_IDX_OFF + gt] = (float)idx;
#pragma unroll
    for (int off = 32; off > 0; off >>= 1) ls += __shfl_down(ls, off, 64);
    if (lane == 0) red[wid] = ls;
    __syncthreads();
    if (tid == 0) {
      double s = 0.0;
#pragma unroll
      for (int i = 0; i < 16; ++i) s += red[i];
      atomicAdd(loss_acc, s);
    }
  }
}

// ---------------- finalize loss ----------------
__global__ void vq_final_k(const double* __restrict__ loss_acc,
                           float* __restrict__ out) {
  out[OUT_LOSS_OFF] =
      (float)(1.25 * (*loss_acc) * (1.0 / (double)((size_t)N_TOK * DIM)));
}

extern "C" void kernel_launch(void* const* d_in, const int* in_sizes, int n_in,
                              void* d_out, int out_size, void* d_ws,
                              size_t ws_size, hipStream_t stream) {
  const float* z = (const float*)d_in[0];
  const float* w = (const float*)d_in[1];
  float* out = (float*)d_out;
  double* loss_acc = (double*)d_ws;  // 8 bytes of ws only

  hipMemsetAsync(d_ws, 0, 8, stream);
  vq_main_k<<<N_TOK / 256, 1024, 0, stream>>>(z, w, out, loss_acc);
  vq_final_k<<<1, 1, 0, stream>>>(loss_acc, out);
}

// Round 5
// 423.921 us; speedup vs baseline: 1.0396x; 1.0396x over previous
//
#include <hip/hip_runtime.h>
#include <stdint.h>

#define N_TOK 262144
#define DIM 64
#define K_CODES 1024
#define OUT_LOSS_OFF (N_TOK * DIM)      // 16777216
#define OUT_IDX_OFF (N_TOK * DIM + 1)   // 16777217

// Screen error budget: fp16 w-term 2^-11*||2z||*||w|| <= 8.9e-5 (||z||<=11.5)
// + fp32 accum/recombine ~2e-6 = eps_s ~ 9.1e-5. Exact-chain own rounding
// eta <= ~1.6e-5. Candidate criterion needs 2*(eps_s+eta) ~ 2.2e-4.
// MARGIN = 4e-4 gives ~1.8x headroom.
#define MARGIN 4e-4f

typedef _Float16 half8 __attribute__((ext_vector_type(8)));
typedef float f32x4 __attribute__((ext_vector_type(4)));
typedef unsigned int uint32x4 __attribute__((ext_vector_type(4)));

// ---- LDS layout (byte offsets into one block) ----
#define SM_WF 0          // fp16 w*1024, 1024 rows x 128B, chunk-XOR swizzled
#define SM_SW2 131072    // float[1024]  ||w_c||^2 (np-pairwise exact)
#define SM_SZ2 135168    // float[256]   ||z_t||^2 (np-pairwise exact)
#define SM_M1 136192     // float[256] best screening d'
#define SM_M2 137216     // float[256] 2nd-best d'
#define SM_M3 138240     // float[256] 3rd-best d' (value only)
#define SM_I1 139264     // int[256] best idx
#define SM_I2 140288     // int[256] 2nd idx
#define SM_IDX 141312    // int[256] final index per token
#define SM_FBC 142336    // int fallback counter
#define SM_FBL 142340    // int[256] fallback token list
#define SM_RED 143368    // double[16] loss partials (8-aligned)
#define SM_FBK 143496    // u64 fallback argmin key
#define SM_BYTES 143504

// numpy pairwise sum of squares over 64 contiguous fp32, STREAMING form:
// identical operation order to the reference pairwise sum (8 accumulators,
// unroll-8, paired combine) but never holds more than 16 values live.
__device__ __forceinline__ float np_sumsq64_stream(const float4* p) {
#pragma clang fp contract(off)
  float r[8];
  {
    float4 a = p[0], b = p[1];
    r[0] = a.x * a.x;
    r[1] = a.y * a.y;
    r[2] = a.z * a.z;
    r[3] = a.w * a.w;
    r[4] = b.x * b.x;
    r[5] = b.y * b.y;
    r[6] = b.z * b.z;
    r[7] = b.w * b.w;
  }
#pragma unroll
  for (int i = 1; i < 8; ++i) {
    float4 a = p[2 * i], b = p[2 * i + 1];
    r[0] += a.x * a.x;
    r[1] += a.y * a.y;
    r[2] += a.z * a.z;
    r[3] += a.w * a.w;
    r[4] += b.x * b.x;
    r[5] += b.y * b.y;
    r[6] += b.z * b.z;
    r[7] += b.w * b.w;
  }
  return ((r[0] + r[1]) + (r[2] + r[3])) + ((r[4] + r[5]) + (r[6] + r[7]));
}

// The ORIGINAL bit-exact distance: d = fl(fl(s_z2+s_w2) - chain64((2z)*w)),
// sequential ascending k. Must match numpy/BLAS exactly -> argmin-identical.
__device__ __forceinline__ float exact_dist(const float* __restrict__ z,
                                            long long t, int c,
                                            const float* __restrict__ w,
                                            float s_z2v, float w2) {
  const float4* zp = (const float4*)(z + (size_t)t * DIM);
  const float4* wp = (const float4*)(w + (size_t)c * DIM);
  float a = 0.f;
#pragma unroll
  for (int i = 0; i < 16; ++i) {
    float4 zv = zp[i];
    float4 pv = wp[i];
    a = __builtin_fmaf(zv.x + zv.x, pv.x, a);
    a = __builtin_fmaf(zv.y + zv.y, pv.y, a);
    a = __builtin_fmaf(zv.z + zv.z, pv.z, a);
    a = __builtin_fmaf(zv.w + zv.w, pv.w, a);
  }
  return (s_z2v + w2) - a;
}

// Exact top-3-values / top-2-indices insert: 5 min/max + 2 cmp + 3 cndmask.
// (R7: replaces ins4's 16-op / 28-reg top-4; the screen only needs
// {i1, i2, value-of-3rd} to decide candidate sets.)
__device__ __forceinline__ void ins3(float d, int c, float& m1, int& i1,
                                     float& m2, int& i2, float& m3) {
  bool b1 = d < m1, b2 = d < m2;
  float u1 = fmaxf(m1, d);
  m1 = fminf(m1, d);
  i2 = b1 ? i1 : (b2 ? c : i2);
  i1 = b1 ? c : i1;
  float u2 = fmaxf(m2, u1);
  m2 = fminf(m2, u1);
  m3 = fminf(m3, u2);
}

// Build one k-half MFMA A-frag pair from 8 z floats: hi = fp16(2z),
// lo = fp16((2z - hi) * 4096). Recombined with exact power-of-2 scales
// (w is scaled by 1024 -> C1=2^-10, C2=2^-22).
__device__ __forceinline__ void make_afrag(float4 a, float4 b, half8& hi,
                                           half8& lo) {
  float v[8] = {a.x, a.y, a.z, a.w, b.x, b.y, b.z, b.w};
  uint32x4 uh, ul;
#pragma unroll
  for (int j = 0; j < 4; ++j) {
    float x0 = v[2 * j] + v[2 * j];
    float x1 = v[2 * j + 1] + v[2 * j + 1];
    _Float16 h0 = (_Float16)x0, h1 = (_Float16)x1;
    float r0 = (x0 - (float)h0) * 4096.f;
    float r1 = (x1 - (float)h1) * 4096.f;
    _Float16 l0 = (_Float16)r0, l1 = (_Float16)r1;
    uh[j] = (unsigned)__builtin_bit_cast(unsigned short, h0) |
            ((unsigned)__builtin_bit_cast(unsigned short, h1) << 16);
    ul[j] = (unsigned)__builtin_bit_cast(unsigned short, l0) |
            ((unsigned)__builtin_bit_cast(unsigned short, l1) << 16);
  }
  hi = __builtin_bit_cast(half8, uh);
  lo = __builtin_bit_cast(half8, ul);
}

// One block = 256 tokens, 1024 threads (16 waves). Screen all 1024 codes via
// mfma_f32_16x16x32_f16; per token keep top-2 (val+idx) + 3rd value.
// Screening distance d' = ||w||^2 - 2z.w  (per-token ||z||^2 shift dropped:
// cannot change per-token ordering). -1024*||w||^2 (exact pow2 scale) is
// folded into the MFMA C-init so d' = mul+fma per pair.
// R7: live state ~50 VGPR < 64 -> no spills (R5/R6 spilled ~40B/thread).
__global__ __attribute__((amdgpu_flat_work_group_size(1024, 1024),
                          amdgpu_waves_per_eu(4, 4))) void vq_main_k(
    const float* __restrict__ z, const float* __restrict__ w,
    float* __restrict__ out, double* __restrict__ loss_acc) {
#pragma clang fp contract(off)
  __shared__ __align__(16) char smem[SM_BYTES];
  char* wf = smem + SM_WF;
  float* sw2 = (float*)(smem + SM_SW2);
  float* sz2 = (float*)(smem + SM_SZ2);
  float* sm1 = (float*)(smem + SM_M1);
  float* sm2 = (float*)(smem + SM_M2);
  float* sm3 = (float*)(smem + SM_M3);
  int* si1 = (int*)(smem + SM_I1);
  int* si2 = (int*)(smem + SM_I2);
  int* sidx = (int*)(smem + SM_IDX);
  int* fbc = (int*)(smem + SM_FBC);
  int* fbl = (int*)(smem + SM_FBL);
  double* red = (double*)(smem + SM_RED);
  unsigned long long* fbk = (unsigned long long*)(smem + SM_FBK);

  const int tid = (int)threadIdx.x;
  const int lane = tid & 63;
  const int wid = tid >> 6;  // 16 waves

  if (tid == 0) *fbc = 0;

  // ---- prologue A: per-code ||w||^2 + fp16(w*1024) staged to LDS ----
  // Streaming: per 8-float chunk, update the 8 pairwise accumulators (exact
  // numpy order) AND pack/store the fp16 chunk. Max ~20 regs live.
  {
    const int c = tid;  // 1024 threads = 1024 codes
    const float4* wp = (const float4*)(w + (size_t)c * DIM);
    float r[8];
#pragma unroll
    for (int ch = 0; ch < 8; ++ch) {
      float4 a = wp[2 * ch], b = wp[2 * ch + 1];
      float x[8] = {a.x, a.y, a.z, a.w, b.x, b.y, b.z, b.w};
      if (ch == 0) {
#pragma unroll
        for (int j = 0; j < 8; ++j) r[j] = x[j] * x[j];
      } else {
#pragma unroll
        for (int j = 0; j < 8; ++j) r[j] += x[j] * x[j];
      }
      uint32x4 pk;
#pragma unroll
      for (int j = 0; j < 4; ++j) {
        _Float16 h0 = (_Float16)(x[2 * j] * 1024.f);
        _Float16 h1 = (_Float16)(x[2 * j + 1] * 1024.f);
        pk[j] = (unsigned)__builtin_bit_cast(unsigned short, h0) |
                ((unsigned)__builtin_bit_cast(unsigned short, h1) << 16);
      }
      // chunk ch holds k = ch*8..+7; stored at slot ch^(c&7) (bank-balanced)
      *(uint32x4*)(wf + c * 128 + ((ch ^ (c & 7)) << 4)) = pk;
    }
    sw2[c] = ((r[0] + r[1]) + (r[2] + r[3])) + ((r[4] + r[5]) + (r[6] + r[7]));
  }
  // ---- prologue B: per-token ||z||^2 (np-pairwise exact, streaming) ----
  if (tid < 256) {
    long long gt = (long long)blockIdx.x * 256 + tid;
    sz2[tid] = np_sumsq64_stream((const float4*)(z + (size_t)gt * DIM));
  }
  __syncthreads();

  // ---- screening: wave handles 16 tokens x all 1024 codes ----
  {
    const int wtok = wid * 16;
    const int g = lane >> 4;     // k-group
    const int c15 = lane & 15;   // code-within-tile
    const int swz = c15 & 7;     // XOR slot: loop-invariant (cc&7 == lane&7)
    // A-frags: token = wtok + c15, k = g*8..+7 (khalf0), 32+g*8 (khalf1)
    half8 ah0, al0, ah1, al1;
    {
      long long gA = ((long long)blockIdx.x * 256 + wtok + c15) * DIM;
      const float* zr = z + gA + g * 8;
      make_afrag(*(const float4*)(zr), *(const float4*)(zr + 4), ah0, al0);
      make_afrag(*(const float4*)(zr + 32), *(const float4*)(zr + 36), ah1,
                 al1);
    }

    float m1[4], m2[4], m3[4];
    int i1[4], i2[4];
#pragma unroll
    for (int r = 0; r < 4; ++r) {
      m1[r] = m2[r] = m3[r] = 3.4e38f;
      i1[r] = i2[r] = 0;
    }

    const float C1N = -1.f / 1024.f;             // undo w*1024, negated
    const float C2N = -1.f / (1024.f * 4096.f);  // undo w*1024 & zlo*4096

#pragma unroll 4
    for (int ct = 0; ct < 64; ++ct) {
      const int cc = (ct << 4) | c15;
      float w2c = sw2[cc];
      const char* wrow = wf + cc * 128;
      half8 b0 = __builtin_bit_cast(
          half8, *(const uint32x4*)(wrow + ((g ^ swz) << 4)));
      half8 b1 = __builtin_bit_cast(
          half8, *(const uint32x4*)(wrow + (((4 + g) ^ swz) << 4)));
      float vm = w2c * -1024.f;  // exact (pow2 scale)
      f32x4 acch = {vm, vm, vm, vm};
      f32x4 accl = {0.f, 0.f, 0.f, 0.f};
      acch = __builtin_amdgcn_mfma_f32_16x16x32_f16(ah0, b0, acch, 0, 0, 0);
      accl = __builtin_amdgcn_mfma_f32_16x16x32_f16(al0, b0, accl, 0, 0, 0);
      acch = __builtin_amdgcn_mfma_f32_16x16x32_f16(ah1, b1, acch, 0, 0, 0);
      accl = __builtin_amdgcn_mfma_f32_16x16x32_f16(al1, b1, accl, 0, 0, 0);
      // acch = sum(hi) - 1024*w2c  =>  d' = w2c - dot = acch*C1N + accl*C2N
#pragma unroll
      for (int r = 0; r < 4; ++r) {
        float t = acch[r] * C1N;
        float d = __builtin_fmaf(accl[r], C2N, t);
        ins3(d, cc, m1[r], i1[r], m2[r], i2[r], m3[r]);
      }
    }

    // butterfly merge across the 16 lanes sharing this token set
#pragma unroll
    for (int s = 1; s <= 8; s <<= 1) {
#pragma unroll
      for (int r = 0; r < 4; ++r) {
        float om1 = __shfl_xor(m1[r], s, 64);
        float om2 = __shfl_xor(m2[r], s, 64);
        float om3 = __shfl_xor(m3[r], s, 64);
        int oi1 = __shfl_xor(i1[r], s, 64);
        int oi2 = __shfl_xor(i2[r], s, 64);
        ins3(om1, oi1, m1[r], i1[r], m2[r], i2[r], m3[r]);
        ins3(om2, oi2, m1[r], i1[r], m2[r], i2[r], m3[r]);
        m3[r] = fminf(m3[r], om3);
      }
    }
    if (c15 == 0) {
#pragma unroll
      for (int r = 0; r < 4; ++r) {
        int tk = wtok + g * 4 + r;
        sm1[tk] = m1[r];
        sm2[tk] = m2[r];
        sm3[tk] = m3[r];
        si1[tk] = i1[r];
        si2[tk] = i2[r];
      }
    }
  }
  __syncthreads();

  // ---- phase 1: resolve index per token (threads 0..255) ----
  if (tid < 256) {
    const int tok = tid;
    float v1 = sm1[tok], v2 = sm2[tok], v3 = sm3[tok];
    float thr = v1 + MARGIN;
    int idx = si1[tok];
    if (v2 <= thr) {
      if (v3 <= thr) {
        // >=3 candidates in margin: rare, full exact scan cooperatively later
        int p = atomicAdd(fbc, 1);
        fbl[p] = tok;
        idx = -1;
      } else {
        long long gt = (long long)blockIdx.x * 256 + tok;
        float sz2v = sz2[tok];
        int ca = si1[tok], cb = si2[tok];
        if (cb < ca) { int t = ca; ca = cb; cb = t; }
        // exact eval ascending index, strict '<' => numpy first-min-wins
        float bd = exact_dist(z, gt, ca, w, sz2v, sw2[ca]);
        idx = ca;
        float d2 = exact_dist(z, gt, cb, w, sz2v, sw2[cb]);
        if (d2 < bd) { bd = d2; idx = cb; }
      }
    }
    if (idx >= 0) sidx[tok] = idx;
  }
  __syncthreads();

  // ---- phase 2: cooperative exact fallback (expected ~0-6 per block) ----
  {
    int nfb = *fbc;
    for (int f = 0; f < nfb; ++f) {
      int tok = fbl[f];
      if (tid == 0) *fbk = ~0ull;
      __syncthreads();
      long long gt = (long long)blockIdx.x * 256 + tok;
      float d = exact_dist(z, gt, tid, w, sz2[tok], sw2[tid]);
      // positive d: float bit pattern is order-preserving; idx in low bits
      unsigned long long key =
          ((unsigned long long)__builtin_bit_cast(unsigned int, d) << 32) |
          (unsigned)tid;
#pragma unroll
      for (int off = 32; off > 0; off >>= 1) {
        unsigned long long o = __shfl_down(key, off, 64);
        key = (o < key) ? o : key;
      }
      if (lane == 0) atomicMin(fbk, key);
      __syncthreads();
      if (tid == 0) sidx[tok] = (int)((*fbk) & 0xffffffffu);
    }
  }
  __syncthreads();

  // ---- phase 3: outputs. thread -> (token, quarter of 16 floats) ----
  {
    const int tok = tid >> 2, q = tid & 3;
    const long long gt = (long long)blockIdx.x * 256 + tok;
    const int idx = sidx[tok];
    const float4* zp = (const float4*)(z + (size_t)gt * DIM) + q * 4;
    const float4* wp = (const float4*)(w + (size_t)idx * DIM) + q * 4;
    float4* op = (float4*)(out + (size_t)gt * DIM) + q * 4;
    double ls = 0.0;
#pragma unroll
    for (int i = 0; i < 4; ++i) {
      float4 wv = wp[i];
      float4 zv = zp[i];
      op[i] = wv;
      double d0 = (double)wv.x - (double)zv.x;
      double d1 = (double)wv.y - (double)zv.y;
      double d2 = (double)wv.z - (double)zv.z;
      double d3 = (double)wv.w - (double)zv.w;
      ls = __builtin_fma(d0, d0, ls);
      ls = __builtin_fma(d1, d1, ls);
      ls = __builtin_fma(d2, d2, ls);
      ls = __builtin_fma(d3, d3, ls);
    }
    if (q == 0) out[OUT_IDX_OFF + gt] = (float)idx;
#pragma unroll
    for (int off = 32; off > 0; off >>= 1) ls += __shfl_down(ls, off, 64);
    if (lane == 0) red[wid] = ls;
    __syncthreads();
    if (tid == 0) {
      double s = 0.0;
#pragma unroll
      for (int i = 0; i < 16; ++i) s += red[i];
      atomicAdd(loss_acc, s);
    }
  }
}

// ---------------- finalize loss ----------------
__global__ void vq_final_k(const double* __restrict__ loss_acc,
                           float* __restrict__ out) {
  out[OUT_LOSS_OFF] =
      (float)(1.25 * (*loss_acc) * (1.0 / (double)((size_t)N_TOK * DIM)));
}

extern "C" void kernel_launch(void* const* d_in, const int* in_sizes, int n_in,
                              void* d_out, int out_size, void* d_ws,
                              size_t ws_size, hipStream_t stream) {
  const float* z = (const float*)d_in[0];
  const float* w = (const float*)d_in[1];
  float* out = (float*)d_out;
  double* loss_acc = (double*)d_ws;  // 8 bytes of ws only

  hipMemsetAsync(d_ws, 0, 8, stream);
  vq_main_k<<<N_TOK / 256, 1024, 0, stream>>>(z, w, out, loss_acc);
  vq_final_k<<<1, 1, 0, stream>>>(loss_acc, out);
}

// Round 6
// 366.895 us; speedup vs baseline: 1.2012x; 1.1554x over previous
//
#include <hip/hip_runtime.h>
#include <stdint.h>

#define N_TOK 262144
#define DIM 64
#define K_CODES 1024
#define OUT_LOSS_OFF (N_TOK * DIM)      // 16777216
#define OUT_IDX_OFF (N_TOK * DIM + 1)   // 16777217

// Hi-only screen error: |screen - real| <= (2^-11 z-cvt + 2^-11 w-cvt)
// * ||2z||*||w|| + fp32 accum ~ 1.9e-4 (||z|| <= 11.5). Candidate rule
// needs THR > 2*eps_s = 3.8e-4. THR = 6.5e-4 (1.7x headroom).
// Screen works on acch = 1024*(dot - w2) directly (exact pow2 scale,
// order-REVERSED): candidate <=> acch >= M1 - 1024*THR = M1 - 0.666.
#define THRA 0.666f
#define WCAP 256

typedef _Float16 half8 __attribute__((ext_vector_type(8)));
typedef float f32x4 __attribute__((ext_vector_type(4)));
typedef unsigned int uint32x4 __attribute__((ext_vector_type(4)));

// ---- LDS layout (byte offsets into one block) ----
#define SM_WF 0          // fp16 w*1024, 1024 rows x 128B, chunk-XOR swizzled
#define SM_SW2 131072    // float[1024]  ||w_c||^2 (np-pairwise exact)
#define SM_SZ2 135168    // float[256]   ||z_t||^2 (np-pairwise exact)
#define SM_WL 136192     // u32[16][WCAP] per-wave candidate lists
#define SM_WC 152576     // int[16] per-wave candidate counters
#define SM_RED 152640    // double[16] loss partials
#define SM_BYTES 152768

// numpy pairwise sum of squares over 64 contiguous fp32, STREAMING form:
// identical operation order to the reference pairwise sum (8 accumulators,
// unroll-8, paired combine) but never holds more than 16 values live.
__device__ __forceinline__ float np_sumsq64_stream(const float4* p) {
#pragma clang fp contract(off)
  float r[8];
  {
    float4 a = p[0], b = p[1];
    r[0] = a.x * a.x;
    r[1] = a.y * a.y;
    r[2] = a.z * a.z;
    r[3] = a.w * a.w;
    r[4] = b.x * b.x;
    r[5] = b.y * b.y;
    r[6] = b.z * b.z;
    r[7] = b.w * b.w;
  }
#pragma unroll
  for (int i = 1; i < 8; ++i) {
    float4 a = p[2 * i], b = p[2 * i + 1];
    r[0] += a.x * a.x;
    r[1] += a.y * a.y;
    r[2] += a.z * a.z;
    r[3] += a.w * a.w;
    r[4] += b.x * b.x;
    r[5] += b.y * b.y;
    r[6] += b.z * b.z;
    r[7] += b.w * b.w;
  }
  return ((r[0] + r[1]) + (r[2] + r[3])) + ((r[4] + r[5]) + (r[6] + r[7]));
}

// The ORIGINAL bit-exact distance: d = fl(fl(s_z2+s_w2) - chain64((2z)*w)),
// sequential ascending k. Matches numpy/BLAS exactly -> argmin-identical.
__device__ __forceinline__ float exact_dist(const float* __restrict__ z,
                                            long long t, int c,
                                            const float* __restrict__ w,
                                            float s_z2v, float w2) {
  const float4* zp = (const float4*)(z + (size_t)t * DIM);
  const float4* wp = (const float4*)(w + (size_t)c * DIM);
  float a = 0.f;
#pragma unroll
  for (int i = 0; i < 16; ++i) {
    float4 zv = zp[i];
    float4 pv = wp[i];
    a = __builtin_fmaf(zv.x + zv.x, pv.x, a);
    a = __builtin_fmaf(zv.y + zv.y, pv.y, a);
    a = __builtin_fmaf(zv.z + zv.z, pv.z, a);
    a = __builtin_fmaf(zv.w + zv.w, pv.w, a);
  }
  return (s_z2v + w2) - a;
}

// Hi-only MFMA A-frag from 8 z floats: fp16(2z).
__device__ __forceinline__ void make_afrag_hi(float4 a, float4 b, half8& hi) {
  float v[8] = {a.x, a.y, a.z, a.w, b.x, b.y, b.z, b.w};
  uint32x4 uh;
#pragma unroll
  for (int j = 0; j < 4; ++j) {
    _Float16 h0 = (_Float16)(v[2 * j] + v[2 * j]);
    _Float16 h1 = (_Float16)(v[2 * j + 1] + v[2 * j + 1]);
    uh[j] = (unsigned)__builtin_bit_cast(unsigned short, h0) |
            ((unsigned)__builtin_bit_cast(unsigned short, h1) << 16);
  }
  hi = __builtin_bit_cast(half8, uh);
}

// One block = 256 tokens, 1024 threads (16 waves). Two-pass MFMA screen:
// pass 1 tracks only the per-token screen MAX of acch (1 v_max/value);
// pass 2 recomputes acch bit-identically and pushes threshold hits into a
// per-wave LDS candidate list. Wave-local resolution: count==1 -> proven
// argmin; count>=2 -> exact lex-(d,idx) min (== numpy first-min-wins).
// No per-value sorted insertion, no loop-carried serial chain, ~40 live
// VGPRs (R3-R5 spilled at 64).
__global__ __attribute__((amdgpu_flat_work_group_size(1024, 1024),
                          amdgpu_waves_per_eu(4, 4))) void vq_main_k(
    const float* __restrict__ z, const float* __restrict__ w,
    float* __restrict__ out, double* __restrict__ loss_acc) {
#pragma clang fp contract(off)
  __shared__ __align__(16) char smem[SM_BYTES];
  char* wf = smem + SM_WF;
  float* sw2 = (float*)(smem + SM_SW2);
  float* sz2 = (float*)(smem + SM_SZ2);
  double* red = (double*)(smem + SM_RED);

  const int tid = (int)threadIdx.x;
  const int lane = tid & 63;
  const int wid = tid >> 6;  // 16 waves

  unsigned* wl = (unsigned*)(smem + SM_WL) + wid * WCAP;
  int* wc = (int*)(smem + SM_WC) + wid;
  if (lane == 0) *wc = 0;

  // ---- prologue A: per-code ||w||^2 + fp16(w*1024) staged to LDS ----
  // Streaming: per 8-float chunk, update the 8 pairwise accumulators (exact
  // numpy order) AND pack/store the fp16 chunk.
  {
    const int c = tid;  // 1024 threads = 1024 codes
    const float4* wp = (const float4*)(w + (size_t)c * DIM);
    float r[8];
#pragma unroll
    for (int ch = 0; ch < 8; ++ch) {
      float4 a = wp[2 * ch], b = wp[2 * ch + 1];
      float x[8] = {a.x, a.y, a.z, a.w, b.x, b.y, b.z, b.w};
      if (ch == 0) {
#pragma unroll
        for (int j = 0; j < 8; ++j) r[j] = x[j] * x[j];
      } else {
#pragma unroll
        for (int j = 0; j < 8; ++j) r[j] += x[j] * x[j];
      }
      uint32x4 pk;
#pragma unroll
      for (int j = 0; j < 4; ++j) {
        _Float16 h0 = (_Float16)(x[2 * j] * 1024.f);
        _Float16 h1 = (_Float16)(x[2 * j + 1] * 1024.f);
        pk[j] = (unsigned)__builtin_bit_cast(unsigned short, h0) |
                ((unsigned)__builtin_bit_cast(unsigned short, h1) << 16);
      }
      // chunk ch holds k = ch*8..+7; stored at slot ch^(c&7) (bank-balanced)
      *(uint32x4*)(wf + c * 128 + ((ch ^ (c & 7)) << 4)) = pk;
    }
    sw2[c] = ((r[0] + r[1]) + (r[2] + r[3])) + ((r[4] + r[5]) + (r[6] + r[7]));
  }
  // ---- prologue B: per-token ||z||^2 (np-pairwise exact, streaming) ----
  if (tid < 256) {
    long long gt = (long long)blockIdx.x * 256 + tid;
    sz2[tid] = np_sumsq64_stream((const float4*)(z + (size_t)gt * DIM));
  }
  __syncthreads();

  // ---- per-wave screen: 16 tokens x all 1024 codes ----
  const int wtok = wid * 16;
  const int g = lane >> 4;     // k-group
  const int c15 = lane & 15;   // code-within-tile
  const int swz = c15 & 7;     // XOR slot: loop-invariant (cc&7 == lane&7)
  half8 ah0, ah1;
  {
    long long gA = ((long long)blockIdx.x * 256 + wtok + c15) * DIM;
    const float* zr = z + gA + g * 8;
    make_afrag_hi(*(const float4*)(zr), *(const float4*)(zr + 4), ah0);
    make_afrag_hi(*(const float4*)(zr + 32), *(const float4*)(zr + 36), ah1);
  }
  const char* b0base = wf + c15 * 128 + ((g ^ swz) << 4);
  const char* b1base = wf + c15 * 128 + (((4 + g) ^ swz) << 4);

  // pass 1: per-token max of acch (acch = 1024*(dot - w2c); larger = closer)
  float M1[4];
#pragma unroll
  for (int r = 0; r < 4; ++r) M1[r] = -3.4e38f;
#pragma unroll 4
  for (int ct = 0; ct < 64; ++ct) {
    float w2c = sw2[(ct << 4) | c15];
    half8 b0 =
        __builtin_bit_cast(half8, *(const uint32x4*)(b0base + ct * 2048));
    half8 b1 =
        __builtin_bit_cast(half8, *(const uint32x4*)(b1base + ct * 2048));
    float vm = w2c * -1024.f;  // exact (pow2 scale)
    f32x4 acch = {vm, vm, vm, vm};
    acch = __builtin_amdgcn_mfma_f32_16x16x32_f16(ah0, b0, acch, 0, 0, 0);
    acch = __builtin_amdgcn_mfma_f32_16x16x32_f16(ah1, b1, acch, 0, 0, 0);
#pragma unroll
    for (int r = 0; r < 4; ++r) M1[r] = fmaxf(M1[r], acch[r]);
  }
  // butterfly all-reduce max over the 16 lanes sharing these 4 token rows
#pragma unroll
  for (int s = 1; s <= 8; s <<= 1) {
#pragma unroll
    for (int r = 0; r < 4; ++r)
      M1[r] = fmaxf(M1[r], __shfl_xor(M1[r], s, 64));
  }
  float thr[4];
#pragma unroll
  for (int r = 0; r < 4; ++r) thr[r] = M1[r] - THRA;

  // pass 2: recompute acch bit-identically; push candidates (tokloc<<10)|cc
  const int tb = g * 4;
#pragma unroll 4
  for (int ct = 0; ct < 64; ++ct) {
    float w2c = sw2[(ct << 4) | c15];
    half8 b0 =
        __builtin_bit_cast(half8, *(const uint32x4*)(b0base + ct * 2048));
    half8 b1 =
        __builtin_bit_cast(half8, *(const uint32x4*)(b1base + ct * 2048));
    float vm = w2c * -1024.f;
    f32x4 acch = {vm, vm, vm, vm};
    acch = __builtin_amdgcn_mfma_f32_16x16x32_f16(ah0, b0, acch, 0, 0, 0);
    acch = __builtin_amdgcn_mfma_f32_16x16x32_f16(ah1, b1, acch, 0, 0, 0);
    const int cc = (ct << 4) | c15;
    bool h0 = acch[0] >= thr[0];
    bool h1 = acch[1] >= thr[1];
    bool h2 = acch[2] >= thr[2];
    bool h3 = acch[3] >= thr[3];
    if (h0 | h1 | h2 | h3) {  // execz-skip in the common case
      if (h0) {
        int p = atomicAdd(wc, 1);
        if (p < WCAP) wl[p] = (unsigned)(((tb + 0) << 10) | cc);
      }
      if (h1) {
        int p = atomicAdd(wc, 1);
        if (p < WCAP) wl[p] = (unsigned)(((tb + 1) << 10) | cc);
      }
      if (h2) {
        int p = atomicAdd(wc, 1);
        if (p < WCAP) wl[p] = (unsigned)(((tb + 2) << 10) | cc);
      }
      if (h3) {
        int p = atomicAdd(wc, 1);
        if (p < WCAP) wl[p] = (unsigned)(((tb + 3) << 10) | cc);
      }
    }
  }

  // Wave-local: drain DS ops (pushes from all lanes of THIS wave), then read.
  asm volatile("s_waitcnt lgkmcnt(0)" ::: "memory");
  int n = *wc;

  // ---- resolution: lanes 0..15 own token wtok+lane ----
  int idxw = 0;
  if (lane < 16) {
    int cnt = 0, code = 0;
    for (int e = 0; e < n && e < WCAP; ++e) {
      unsigned u = wl[e];  // same addr across lanes -> LDS broadcast
      if ((int)(u >> 10) == lane) {
        cnt++;
        code = (int)(u & 1023u);
      }
    }
    if (n > WCAP) {
      // pathological overflow: full exact scan, ascending c, strict '<'
      long long gt = (long long)blockIdx.x * 256 + wtok + lane;
      float sz2v = sz2[wtok + lane];
      float bd = 3.4e38f;
      code = 0;
      for (int c = 0; c < K_CODES; ++c) {
        float d = exact_dist(z, gt, c, w, sz2v, sw2[c]);
        if (d < bd) {
          bd = d;
          code = c;
        }
      }
    } else if (cnt >= 2) {
      // exact lex-(d, idx) min over candidates == numpy first-min-wins
      long long gt = (long long)blockIdx.x * 256 + wtok + lane;
      float sz2v = sz2[wtok + lane];
      float bd = 3.4e38f;
      int bi = K_CODES;
      for (int e = 0; e < n; ++e) {
        unsigned u = wl[e];
        if ((int)(u >> 10) == lane) {
          int c = (int)(u & 1023u);
          float d = exact_dist(z, gt, c, w, sz2v, sw2[c]);
          if (d < bd || (d == bd && c < bi)) {
            bd = d;
            bi = c;
          }
        }
      }
      code = bi;
    }
    idxw = code;
  }
  const int idx = __shfl(idxw, lane >> 2, 64);

  // ---- outputs (per-wave): lane -> (token = wtok + lane>>2, quarter) ----
  {
    const int tok = wtok + (lane >> 2), q = lane & 3;
    const long long gt = (long long)blockIdx.x * 256 + tok;
    const float4* zp = (const float4*)(z + (size_t)gt * DIM) + q * 4;
    const float4* wp = (const float4*)(w + (size_t)idx * DIM) + q * 4;
    float4* op = (float4*)(out + (size_t)gt * DIM) + q * 4;
    double ls = 0.0;
#pragma unroll
    for (int i = 0; i < 4; ++i) {
      float4 wv = wp[i];
      float4 zv = zp[i];
      op[i] = wv;
      double d0 = (double)wv.x - (double)zv.x;
      double d1 = (double)wv.y - (double)zv.y;
      double d2 = (double)wv.z - (double)zv.z;
      double d3 = (double)wv.w - (double)zv.w;
      ls = __builtin_fma(d0, d0, ls);
      ls = __builtin_fma(d1, d1, ls);
      ls = __builtin_fma(d2, d2, ls);
      ls = __builtin_fma(d3, d3, ls);
    }
    if (q == 0) out[OUT_IDX_OFF + gt] = (float)idx;
#pragma unroll
    for (int off = 32; off > 0; off >>= 1) ls += __shfl_down(ls, off, 64);
    if (lane == 0) red[wid] = ls;
  }
  __syncthreads();
  if (tid == 0) {
    double s = 0.0;
#pragma unroll
    for (int i = 0; i < 16; ++i) s += red[i];
    atomicAdd(loss_acc, s);
  }
}

// ---------------- finalize loss ----------------
__global__ void vq_final_k(const double* __restrict__ loss_acc,
                           float* __restrict__ out) {
  out[OUT_LOSS_OFF] =
      (float)(1.25 * (*loss_acc) * (1.0 / (double)((size_t)N_TOK * DIM)));
}

extern "C" void kernel_launch(void* const* d_in, const int* in_sizes, int n_in,
                              void* d_out, int out_size, void* d_ws,
                              size_t ws_size, hipStream_t stream) {
  const float* z = (const float*)d_in[0];
  const float* w = (const float*)d_in[1];
  float* out = (float*)d_out;
  double* loss_acc = (double*)d_ws;  // 8 bytes of ws only

  hipMemsetAsync(d_ws, 0, 8, stream);
  vq_main_k<<<N_TOK / 256, 1024, 0, stream>>>(z, w, out, loss_acc);
  vq_final_k<<<1, 1, 0, stream>>>(loss_acc, out);
}